// Round 1
// baseline (12592.873 us; speedup 1.0000x reference)
//
#include <hip/hip_runtime.h>
#include <cstdint>

typedef unsigned short ushort_t;
typedef __attribute__((ext_vector_type(8))) short short8;
typedef __attribute__((ext_vector_type(4))) float f32x4;

#define T_STEPS 512
#define BATCH   64
#define IDIM    512
#define HIDDEN  1024
#define NWG     64
#define BH      (BATCH*HIDDEN)   // 65536

__device__ __forceinline__ ushort_t f2bf(float f) {
  unsigned int x = __float_as_uint(f);
  unsigned int r = (x + 0x7fffu + ((x >> 16) & 1u)) >> 16;
  return (ushort_t)r;
}
__device__ __forceinline__ float sigmoid_f(float x) { return 1.f / (1.f + __expf(-x)); }
__device__ __forceinline__ float tanh_f(float x)    { return 1.f - 2.f / (1.f + __expf(2.f * x)); }

// ---------------- weight conversion: f32 -> bf16, split h-part / x-part ----
__global__ __launch_bounds__(256) void convert_weights(
    const float* __restrict__ Wz, const float* __restrict__ Wh,
    ushort_t* __restrict__ Wzh, ushort_t* __restrict__ Wzx,
    ushort_t* __restrict__ Whh, ushort_t* __restrict__ Whx)
{
  int j = blockIdx.x;
  const float* W = blockIdx.y ? Wh : Wz;
  ushort_t* Bh = blockIdx.y ? Whh : Wzh;
  ushort_t* Bx = blockIdx.y ? Whx : Wzx;
  const float* row = W + (size_t)j * (HIDDEN + IDIM);
  for (int c = threadIdx.x; c < HIDDEN + IDIM; c += 256) {
    ushort_t v = f2bf(row[c]);
    if (c < HIDDEN) Bh[(size_t)j * HIDDEN + c] = v;
    else            Bx[(size_t)j * IDIM + (c - HIDDEN)] = v;
  }
}

// ---------------- phase 1: Gx = x @ Wx^T + b  (two GEMMs via blockIdx.z) ----
// out[t*B+b][j], stored into the Z (which=0) / R (which=1) regions of d_out.
__global__ __launch_bounds__(256) void gx_gemm(
    const float* __restrict__ x,
    const ushort_t* __restrict__ Wzx, const ushort_t* __restrict__ Whx,
    const float* __restrict__ bz, const float* __restrict__ bh,
    float* __restrict__ outZ, float* __restrict__ outR)
{
  const int which = blockIdx.z;
  const ushort_t* W = which ? Whx : Wzx;
  const float* bias = which ? bh : bz;
  float* out = which ? outR : outZ;
  const int m0 = blockIdx.x * 64;
  const int n0 = blockIdx.y * 64;
  __shared__ ushort_t As[64 * 40];   // 32 k padded to 40 (bank-conflict-free)
  __shared__ ushort_t Bs[64 * 40];
  const int tid = threadIdx.x;
  const int lane = tid & 63, w4 = tid >> 6;
  const int row = tid >> 2, q = tid & 3;
  f32x4 acc[4] = {{0,0,0,0},{0,0,0,0},{0,0,0,0},{0,0,0,0}};
  for (int kk = 0; kk < IDIM; kk += 32) {
    const float* xs = &x[(size_t)(m0 + row) * IDIM + kk + q * 8];
    float4 f0 = *(const float4*)xs;
    float4 f1 = *(const float4*)(xs + 4);
    short8 av;
    av[0]=f2bf(f0.x); av[1]=f2bf(f0.y); av[2]=f2bf(f0.z); av[3]=f2bf(f0.w);
    av[4]=f2bf(f1.x); av[5]=f2bf(f1.y); av[6]=f2bf(f1.z); av[7]=f2bf(f1.w);
    short8 bv = *(const short8*)&W[(size_t)(n0 + row) * IDIM + kk + q * 8];
    __syncthreads();
    *(short8*)&As[row * 40 + q * 8] = av;
    *(short8*)&Bs[row * 40 + q * 8] = bv;
    __syncthreads();
    short8 af = *(const short8*)&As[(w4 * 16 + (lane & 15)) * 40 + (lane >> 4) * 8];
    #pragma unroll
    for (int c = 0; c < 4; ++c) {
      short8 bf = *(const short8*)&Bs[(c * 16 + (lane & 15)) * 40 + (lane >> 4) * 8];
      acc[c] = __builtin_amdgcn_mfma_f32_16x16x32_bf16(af, bf, acc[c], 0, 0, 0);
    }
  }
  #pragma unroll
  for (int c = 0; c < 4; ++c) {
    int j = n0 + c * 16 + (lane & 15);
    float bv = bias[j];
    #pragma unroll
    for (int r = 0; r < 4; ++r) {
      int m = m0 + w4 * 16 + (lane >> 4) * 4 + r;
      out[(size_t)m * HIDDEN + j] = acc[c][r] + bv;
    }
  }
}

// ---------------- persistent recurrent kernel -----------------------------
__device__ __forceinline__ void wait_all(int* flags, int target) {
  if (threadIdx.x < NWG) {
    while (__hip_atomic_load(&flags[threadIdx.x * 32], __ATOMIC_RELAXED,
                             __HIP_MEMORY_SCOPE_AGENT) < target)
      __builtin_amdgcn_s_sleep(1);
  }
  __syncthreads();
  __threadfence();   // acquire: invalidate stale cached lines before data reads
}

__device__ __forceinline__ void arrive(int* flags, int w, int val) {
  __syncthreads();                 // all threads' writes issued & workgroup-visible
  if (threadIdx.x == 0) {
    __threadfence();               // release: make writes agent-visible
    __hip_atomic_store(&flags[w * 32], val, __ATOMIC_RELAXED, __HIP_MEMORY_SCOPE_AGENT);
  }
}

__global__ __launch_bounds__(256) void gru_persist(
    const ushort_t* __restrict__ Wzh, const ushort_t* __restrict__ Whh,
    float* __restrict__ H, float* __restrict__ Z, float* __restrict__ R,
    ushort_t* __restrict__ h_buf, ushort_t* __restrict__ ghb,
    int* __restrict__ flags)
{
  extern __shared__ ushort_t smem[];   // [2][16][1024] bf16, XOR-swizzled rows
  const int w = blockIdx.x;
  const int tid = threadIdx.x;
  const int lane = tid & 63, w4 = tid >> 6;
  const int jbase = w * 16;

  // load this WG's 16-column weight slices into LDS (swizzled: k ^= (row&7)<<3)
  for (int c = tid; c < 2048; c += 256) {
    int row = c >> 7;
    int k = (c & 127) * 8;
    int sw = row * HIDDEN + (k ^ ((row & 7) << 3));
    *(short8*)&smem[sw]         = *(const short8*)&Wzh[(size_t)(jbase + row) * HIDDEN + k];
    *(short8*)&smem[16384 + sw] = *(const short8*)&Whh[(size_t)(jbase + row) * HIDDEN + k];
  }

  const int jcol  = jbase + (lane & 15);
  const int brow0 = w4 * 16 + ((lane >> 4) << 2);
  #pragma unroll
  for (int r = 0; r < 4; ++r) {
    h_buf[(brow0 + r) * HIDDEN + jcol] = 0;          // h0 = 0 (bf16 broadcast buf)
    H[(size_t)(brow0 + r) * HIDDEN + jcol] = 0.f;    // H[0] = 0
  }
  float hreg[4] = {0.f, 0.f, 0.f, 0.f};              // f32 state, thread-owned
  arrive(flags, w, 1);

  const int koff = (lane >> 4) * 8;
  const int arow = (w4 * 16 + (lane & 15)) * HIDDEN;   // A-frag batch row
  const int wrow = (lane & 15);                        // weight row within slice
  const int wswz = (wrow & 7) << 3;
  const int wbase = wrow * HIDDEN;

  for (int t = 0; t < T_STEPS; ++t) {
    const size_t zoff = (size_t)t * BH;
    float gz[4];
    #pragma unroll
    for (int r = 0; r < 4; ++r) gz[r] = Z[zoff + (brow0 + r) * HIDDEN + jcol]; // Gxz prefetch
    wait_all(flags, 2 * t + 1);

    // phase A: z-gate matvec over full h
    f32x4 acc = {0, 0, 0, 0};
    #pragma unroll
    for (int kk = 0; kk < HIDDEN; kk += 32) {
      short8 a = *(const short8*)&h_buf[arow + kk + koff];
      short8 b = *(const short8*)&smem[wbase + ((kk + koff) ^ wswz)];
      acc = __builtin_amdgcn_mfma_f32_16x16x32_bf16(a, b, acc, 0, 0, 0);
    }
    float g[4];
    #pragma unroll
    for (int r = 0; r < 4; ++r) {
      g[r] = sigmoid_f(acc[r] + gz[r]);
      Z[zoff + (brow0 + r) * HIDDEN + jcol] = g[r];
      ghb[(brow0 + r) * HIDDEN + jcol] = f2bf(g[r] * hreg[r]);
    }
    arrive(flags, w, 2 * t + 2);

    float gh[4];
    #pragma unroll
    for (int r = 0; r < 4; ++r) gh[r] = R[zoff + (brow0 + r) * HIDDEN + jcol]; // Gxh prefetch
    wait_all(flags, 2 * t + 2);

    // phase B: candidate matvec over full g*h
    f32x4 acc2 = {0, 0, 0, 0};
    #pragma unroll
    for (int kk = 0; kk < HIDDEN; kk += 32) {
      short8 a = *(const short8*)&ghb[arow + kk + koff];
      short8 b = *(const short8*)&smem[16384 + wbase + ((kk + koff) ^ wswz)];
      acc2 = __builtin_amdgcn_mfma_f32_16x16x32_bf16(a, b, acc2, 0, 0, 0);
    }
    const size_t hoff = (size_t)(t + 1) * BH;
    #pragma unroll
    for (int r = 0; r < 4; ++r) {
      float cand = tanh_f(acc2[r] + gh[r]);
      float hn = (1.f - g[r]) * hreg[r] + g[r] * cand;
      hreg[r] = hn;
      H[hoff + (brow0 + r) * HIDDEN + jcol] = hn;
      h_buf[(brow0 + r) * HIDDEN + jcol] = f2bf(hn);
      R[zoff + (brow0 + r) * HIDDEN + jcol] = g[r];
    }
    arrive(flags, w, 2 * t + 3);
  }
}

// ---------------- host launcher -------------------------------------------
extern "C" void kernel_launch(void* const* d_in, const int* in_sizes, int n_in,
                              void* d_out, int out_size, void* d_ws, size_t ws_size,
                              hipStream_t stream) {
  (void)in_sizes; (void)n_in; (void)out_size; (void)ws_size;
  const float* x  = (const float*)d_in[0];
  const float* Wz = (const float*)d_in[1];
  const float* bz = (const float*)d_in[2];
  const float* Wh = (const float*)d_in[3];
  const float* bh = (const float*)d_in[4];

  float* H = (float*)d_out;
  float* Z = H + (size_t)(T_STEPS + 1) * BH;
  float* R = Z + (size_t)T_STEPS * BH;

  char* ws = (char*)d_ws;
  int*      flags = (int*)ws;                                   // 16 KB
  ushort_t* h_buf = (ushort_t*)(ws + 16384);                    // 128 KB
  ushort_t* ghb   = (ushort_t*)(ws + 16384 + 131072);           // 128 KB
  ushort_t* Wzh   = (ushort_t*)(ws + 16384 + 2 * 131072);       // 2 MB
  ushort_t* Whh   = Wzh + (size_t)HIDDEN * HIDDEN;              // 2 MB
  ushort_t* Wzx   = Whh + (size_t)HIDDEN * HIDDEN;              // 1 MB
  ushort_t* Whx   = Wzx + (size_t)HIDDEN * IDIM;                // 1 MB

  hipMemsetAsync(flags, 0, 16384, stream);
  convert_weights<<<dim3(HIDDEN, 2), 256, 0, stream>>>(Wz, Wh, Wzh, Wzx, Whh, Whx);
  gx_gemm<<<dim3(T_STEPS * BATCH / 64, HIDDEN / 64, 2), 256, 0, stream>>>(
      x, Wzx, Whx, bz, bh, Z, R);
  gru_persist<<<NWG, 256, 65536, stream>>>(Wzh, Whh, H, Z, R, h_buf, ghb, flags);
}

// Round 2
// 11694.096 us; speedup vs baseline: 1.0769x; 1.0769x over previous
//
#include <hip/hip_runtime.h>
#include <cstdint>

typedef unsigned short ushort_t;
typedef __attribute__((ext_vector_type(8))) short short8;
typedef __attribute__((ext_vector_type(4))) float f32x4;
typedef unsigned long long u64;

#define T_STEPS 512
#define BATCH   64
#define IDIM    512
#define HIDDEN  1024
#define NWGP    32          // persistent workgroups
#define NC      32          // output columns per WG
#define BH      (BATCH*HIDDEN)   // 65536

__device__ __forceinline__ ushort_t f2bf(float f) {
  unsigned int x = __float_as_uint(f);
  unsigned int r = (x + 0x7fffu + ((x >> 16) & 1u)) >> 16;
  return (ushort_t)r;
}
__device__ __forceinline__ float sigmoid_f(float x) { return 1.f / (1.f + __expf(-x)); }
__device__ __forceinline__ float tanh_f(float x)    { return 1.f - 2.f / (1.f + __expf(2.f * x)); }

union S8U { short8 s; u64 u[2]; };

// coherent (LLC, sc1) 16B load as two 8B relaxed agent atomics
__device__ __forceinline__ short8 coh_load16(const u64* p) {
  S8U r;
  r.u[0] = __hip_atomic_load(p,     __ATOMIC_RELAXED, __HIP_MEMORY_SCOPE_AGENT);
  r.u[1] = __hip_atomic_load(p + 1, __ATOMIC_RELAXED, __HIP_MEMORY_SCOPE_AGENT);
  return r.s;
}

// ---------------- weight conversion: f32 -> bf16, split h-part / x-part ----
__global__ __launch_bounds__(256) void convert_weights(
    const float* __restrict__ Wz, const float* __restrict__ Wh,
    ushort_t* __restrict__ Wzh, ushort_t* __restrict__ Wzx,
    ushort_t* __restrict__ Whh, ushort_t* __restrict__ Whx)
{
  int j = blockIdx.x;
  const float* W = blockIdx.y ? Wh : Wz;
  ushort_t* Bh = blockIdx.y ? Whh : Wzh;
  ushort_t* Bx = blockIdx.y ? Whx : Wzx;
  const float* row = W + (size_t)j * (HIDDEN + IDIM);
  for (int c = threadIdx.x; c < HIDDEN + IDIM; c += 256) {
    ushort_t v = f2bf(row[c]);
    if (c < HIDDEN) Bh[(size_t)j * HIDDEN + c] = v;
    else            Bx[(size_t)j * IDIM + (c - HIDDEN)] = v;
  }
}

// ---------------- phase 1: Gx = x @ Wx^T + b  (two GEMMs via blockIdx.z) ----
__global__ __launch_bounds__(256) void gx_gemm(
    const float* __restrict__ x,
    const ushort_t* __restrict__ Wzx, const ushort_t* __restrict__ Whx,
    const float* __restrict__ bz, const float* __restrict__ bh,
    float* __restrict__ outZ, float* __restrict__ outR)
{
  const int which = blockIdx.z;
  const ushort_t* W = which ? Whx : Wzx;
  const float* bias = which ? bh : bz;
  float* out = which ? outR : outZ;
  const int m0 = blockIdx.x * 64;
  const int n0 = blockIdx.y * 64;
  __shared__ ushort_t As[64 * 40];
  __shared__ ushort_t Bs[64 * 40];
  const int tid = threadIdx.x;
  const int lane = tid & 63, w4 = tid >> 6;
  const int row = tid >> 2, q = tid & 3;
  f32x4 acc[4] = {{0,0,0,0},{0,0,0,0},{0,0,0,0},{0,0,0,0}};
  for (int kk = 0; kk < IDIM; kk += 32) {
    const float* xs = &x[(size_t)(m0 + row) * IDIM + kk + q * 8];
    float4 f0 = *(const float4*)xs;
    float4 f1 = *(const float4*)(xs + 4);
    short8 av;
    av[0]=f2bf(f0.x); av[1]=f2bf(f0.y); av[2]=f2bf(f0.z); av[3]=f2bf(f0.w);
    av[4]=f2bf(f1.x); av[5]=f2bf(f1.y); av[6]=f2bf(f1.z); av[7]=f2bf(f1.w);
    short8 bv = *(const short8*)&W[(size_t)(n0 + row) * IDIM + kk + q * 8];
    __syncthreads();
    *(short8*)&As[row * 40 + q * 8] = av;
    *(short8*)&Bs[row * 40 + q * 8] = bv;
    __syncthreads();
    short8 af = *(const short8*)&As[(w4 * 16 + (lane & 15)) * 40 + (lane >> 4) * 8];
    #pragma unroll
    for (int c = 0; c < 4; ++c) {
      short8 bf = *(const short8*)&Bs[(c * 16 + (lane & 15)) * 40 + (lane >> 4) * 8];
      acc[c] = __builtin_amdgcn_mfma_f32_16x16x32_bf16(af, bf, acc[c], 0, 0, 0);
    }
  }
  #pragma unroll
  for (int c = 0; c < 4; ++c) {
    int j = n0 + c * 16 + (lane & 15);
    float bv = bias[j];
    #pragma unroll
    for (int r = 0; r < 4; ++r) {
      int m = m0 + w4 * 16 + (lane >> 4) * 4 + r;
      out[(size_t)m * HIDDEN + j] = acc[c][r] + bv;
    }
  }
}

// ---------------- persistent recurrent kernel (fence-free, sc1 comms) ------
__global__ __launch_bounds__(256) void gru_persist(
    const ushort_t* __restrict__ Wzh, const ushort_t* __restrict__ Whh,
    float* __restrict__ H, float* __restrict__ Z, float* __restrict__ R,
    u64* __restrict__ h_buf, u64* __restrict__ ghb, int* __restrict__ ctr)
{
  extern __shared__ ushort_t smem[];        // Wz slice [32][1024], Wh slice, 2 scratches
  ushort_t* scrA = smem + 65536;            // [64][48] ushort
  ushort_t* scrB = scrA + 64 * 48;
  const int w = blockIdx.x;
  const int tid = threadIdx.x;
  const int lane = tid & 63;
  const int wv = tid >> 6;                  // wave 0..3
  const int jbase = w * NC;

  // stage this WG's weight slices (XOR-swizzled rows: k ^= (row&7)<<3)
  for (int c = tid; c < NC * 128; c += 256) {
    int row = c >> 7, k8 = (c & 127) * 8;
    int dst = row * 1024 + (k8 ^ ((row & 7) << 3));
    *(short8*)&smem[dst]         = *(const short8*)&Wzh[(size_t)(jbase + row) * 1024 + k8];
    *(short8*)&smem[32768 + dst] = *(const short8*)&Whh[(size_t)(jbase + row) * 1024 + k8];
  }

  // writer-thread mapping (store layout): row = tid>>2, cols scc..scc+7
  const int srow = tid >> 2, scc = (tid & 3) * 8;
  u64* hwp = h_buf + srow * 256 + ((jbase + scc) >> 2);
  u64* gwp = ghb   + srow * 256 + ((jbase + scc) >> 2);

  // init: h0 = 0 (coherent), H[0] = 0 (normal)
  {
    __hip_atomic_store(hwp,     0ull, __ATOMIC_RELAXED, __HIP_MEMORY_SCOPE_AGENT);
    __hip_atomic_store(hwp + 1, 0ull, __ATOMIC_RELAXED, __HIP_MEMORY_SCOPE_AGENT);
    float4 z4 = {0.f, 0.f, 0.f, 0.f};
    *(float4*)&H[(size_t)srow * 1024 + jbase + scc]     = z4;
    *(float4*)&H[(size_t)srow * 1024 + jbase + scc + 4] = z4;
  }
  asm volatile("s_waitcnt vmcnt(0)" ::: "memory");
  __syncthreads();
  if (tid == 0) __hip_atomic_fetch_add(ctr, 1, __ATOMIC_RELAXED, __HIP_MEMORY_SCOPE_AGENT);

  // compute-thread constants
  const int koff = (lane >> 4) * 8;
  const int ar = wv * 16 + (lane & 15);     // A-fragment batch row
  const int abase = ar * 256;               // u64 index of that row
  const int lc = lane & 15;
  const int m0 = wv * 16 + (lane >> 4) * 4; // output batch rows m0..m0+3
  const int wb0 = lc * 1024,        wb1 = (16 + lc) * 1024;
  const int sz0 = (lc & 7) << 3,    sz1 = ((16 + lc) & 7) << 3;

  float hreg[2][4] = {{0.f,0.f,0.f,0.f},{0.f,0.f,0.f,0.f}};

  for (int t = 0; t < T_STEPS; ++t) {
    const size_t zoff = (size_t)t * BH;

    // prefetch Gxz (overlaps with poll)
    float gz[2][4];
    #pragma unroll
    for (int c = 0; c < 2; ++c)
      #pragma unroll
      for (int r = 0; r < 4; ++r)
        gz[c][r] = Z[zoff + (size_t)(m0 + r) * 1024 + jbase + c * 16 + lc];

    { int target = NWGP * (2 * t + 1);
      if (tid < 64)
        while (__hip_atomic_load(ctr, __ATOMIC_RELAXED, __HIP_MEMORY_SCOPE_AGENT) < target)
          __builtin_amdgcn_s_sleep(1);
      __syncthreads(); }

    // phase A: z-gate matvec over full h (coherent loads)
    f32x4 acc0 = {0,0,0,0}, acc1 = {0,0,0,0};
    #pragma unroll
    for (int kk = 0; kk < HIDDEN; kk += 32) {
      int k = kk + koff;
      short8 a  = coh_load16(h_buf + abase + (k >> 2));
      short8 b0 = *(const short8*)&smem[wb0 + (k ^ sz0)];
      short8 b1 = *(const short8*)&smem[wb1 + (k ^ sz1)];
      acc0 = __builtin_amdgcn_mfma_f32_16x16x32_bf16(a, b0, acc0, 0, 0, 0);
      acc1 = __builtin_amdgcn_mfma_f32_16x16x32_bf16(a, b1, acc1, 0, 0, 0);
    }
    float g[2][4];
    #pragma unroll
    for (int c = 0; c < 2; ++c)
      #pragma unroll
      for (int r = 0; r < 4; ++r) {
        float gv = sigmoid_f((c ? acc1[r] : acc0[r]) + gz[c][r]);
        g[c][r] = gv;
        Z[zoff + (size_t)(m0 + r) * 1024 + jbase + c * 16 + lc] = gv;
        scrA[(m0 + r) * 48 + c * 16 + lc] = f2bf(gv * hreg[c][r]);
      }
    __syncthreads();
    { S8U v; v.s = *(const short8*)&scrA[srow * 48 + scc];
      __hip_atomic_store(gwp,     v.u[0], __ATOMIC_RELAXED, __HIP_MEMORY_SCOPE_AGENT);
      __hip_atomic_store(gwp + 1, v.u[1], __ATOMIC_RELAXED, __HIP_MEMORY_SCOPE_AGENT); }
    asm volatile("s_waitcnt vmcnt(0)" ::: "memory");
    __syncthreads();
    if (tid == 0) __hip_atomic_fetch_add(ctr, 1, __ATOMIC_RELAXED, __HIP_MEMORY_SCOPE_AGENT);

    // prefetch Gxh (overlaps with poll)
    float gh[2][4];
    #pragma unroll
    for (int c = 0; c < 2; ++c)
      #pragma unroll
      for (int r = 0; r < 4; ++r)
        gh[c][r] = R[zoff + (size_t)(m0 + r) * 1024 + jbase + c * 16 + lc];

    { int target = NWGP * (2 * t + 2);
      if (tid < 64)
        while (__hip_atomic_load(ctr, __ATOMIC_RELAXED, __HIP_MEMORY_SCOPE_AGENT) < target)
          __builtin_amdgcn_s_sleep(1);
      __syncthreads(); }

    // phase B: candidate matvec over full g*h
    f32x4 acc2 = {0,0,0,0}, acc3 = {0,0,0,0};
    #pragma unroll
    for (int kk = 0; kk < HIDDEN; kk += 32) {
      int k = kk + koff;
      short8 a  = coh_load16(ghb + abase + (k >> 2));
      short8 b0 = *(const short8*)&smem[32768 + wb0 + (k ^ sz0)];
      short8 b1 = *(const short8*)&smem[32768 + wb1 + (k ^ sz1)];
      acc2 = __builtin_amdgcn_mfma_f32_16x16x32_bf16(a, b0, acc2, 0, 0, 0);
      acc3 = __builtin_amdgcn_mfma_f32_16x16x32_bf16(a, b1, acc3, 0, 0, 0);
    }
    const size_t hoff = (size_t)(t + 1) * BH;
    #pragma unroll
    for (int c = 0; c < 2; ++c)
      #pragma unroll
      for (int r = 0; r < 4; ++r) {
        float cand = tanh_f((c ? acc3[r] : acc2[r]) + gh[c][r]);
        float hn = (1.f - g[c][r]) * hreg[c][r] + g[c][r] * cand;
        hreg[c][r] = hn;
        H[hoff + (size_t)(m0 + r) * 1024 + jbase + c * 16 + lc] = hn;
        R[zoff + (size_t)(m0 + r) * 1024 + jbase + c * 16 + lc] = g[c][r];
        scrB[(m0 + r) * 48 + c * 16 + lc] = f2bf(hn);
      }
    __syncthreads();
    { S8U v; v.s = *(const short8*)&scrB[srow * 48 + scc];
      __hip_atomic_store(hwp,     v.u[0], __ATOMIC_RELAXED, __HIP_MEMORY_SCOPE_AGENT);
      __hip_atomic_store(hwp + 1, v.u[1], __ATOMIC_RELAXED, __HIP_MEMORY_SCOPE_AGENT); }
    asm volatile("s_waitcnt vmcnt(0)" ::: "memory");
    __syncthreads();
    if (tid == 0) __hip_atomic_fetch_add(ctr, 1, __ATOMIC_RELAXED, __HIP_MEMORY_SCOPE_AGENT);
  }
}

// ---------------- host launcher -------------------------------------------
extern "C" void kernel_launch(void* const* d_in, const int* in_sizes, int n_in,
                              void* d_out, int out_size, void* d_ws, size_t ws_size,
                              hipStream_t stream) {
  (void)in_sizes; (void)n_in; (void)out_size; (void)ws_size;
  const float* x  = (const float*)d_in[0];
  const float* Wz = (const float*)d_in[1];
  const float* bz = (const float*)d_in[2];
  const float* Wh = (const float*)d_in[3];
  const float* bh = (const float*)d_in[4];

  float* H = (float*)d_out;
  float* Z = H + (size_t)(T_STEPS + 1) * BH;
  float* R = Z + (size_t)T_STEPS * BH;

  char* ws = (char*)d_ws;
  int*      ctr   = (int*)ws;                                   // 16 KB region
  u64*      h_buf = (u64*)(ws + 16384);                         // 128 KB
  u64*      ghb   = (u64*)(ws + 16384 + 131072);                // 128 KB
  ushort_t* Wzh   = (ushort_t*)(ws + 16384 + 2 * 131072);       // 2 MB
  ushort_t* Whh   = Wzh + (size_t)HIDDEN * HIDDEN;              // 2 MB
  ushort_t* Wzx   = Whh + (size_t)HIDDEN * HIDDEN;              // 1 MB
  ushort_t* Whx   = Wzx + (size_t)HIDDEN * IDIM;                // 1 MB

  hipFuncSetAttribute((const void*)gru_persist,
                      hipFuncAttributeMaxDynamicSharedMemorySize, 143360);

  hipMemsetAsync(ctr, 0, 16384, stream);
  convert_weights<<<dim3(HIDDEN, 2), 256, 0, stream>>>(Wz, Wh, Wzh, Wzx, Whh, Whx);
  gx_gemm<<<dim3(T_STEPS * BATCH / 64, HIDDEN / 64, 2), 256, 0, stream>>>(
      x, Wzx, Whx, bz, bh, Z, R);
  gru_persist<<<NWGP, 256, 143360, stream>>>(Wzh, Whh, H, Z, R, h_buf, ghb, ctr);
}